// Round 1
// baseline (11.140 us; speedup 1.0000x reference)
//
#include <hip/hip_runtime.h>
#include <math.h>

// Closed-form evaluation of the slab-ocean affine recurrence:
//   U[t+1] = c*U[t] + d,  U[0] = 0
//   => U[t] = d * (1 - c^t) / (1 - c)
// c = 1 + dt*(-i*fc - K1), d = dt*K0*(TAx + i*TAy), K = exp(pk).
// Fully parallel over t; c^t computed in double via polar form.

__global__ void slab1d_closed_form_kernel(const float* __restrict__ pk,
                                          const float* __restrict__ TAx,
                                          const float* __restrict__ TAy,
                                          const float* __restrict__ fc,
                                          const int* __restrict__ dtp,
                                          float* __restrict__ out,
                                          int nt) {
    int t = blockIdx.x * blockDim.x + threadIdx.x;
    if (t >= nt) return;

    // Wave-uniform scalar setup (all loads hit L1/L2; cheap).
    double dt   = (double)dtp[0];
    double K0   = exp((double)pk[0]);
    double K1   = exp((double)pk[1]);
    double fcd  = (double)fc[0];

    double c_re = 1.0 - dt * K1;   // Re(c)
    double c_im = -dt * fcd;       // Im(c)
    double d_re = dt * K0 * (double)TAx[0];
    double d_im = dt * K0 * (double)TAy[0];

    // c^t via polar form: c = r e^{i theta}; c^t = e^{t log r} e^{i t theta}
    double r2    = c_re * c_re + c_im * c_im;
    double logr  = 0.5 * log(r2);
    double theta = atan2(c_im, c_re);

    double td  = (double)t;
    double rt  = exp(td * logr);
    double ang = td * theta;
    double s, c;
    sincos(ang, &s, &c);
    double ct_re = rt * c;
    double ct_im = rt * s;

    // num = 1 - c^t
    double n_re = 1.0 - ct_re;
    double n_im = -ct_im;
    // den = 1 - c  (= dt*K1 + i*dt*fc)
    double q_re = 1.0 - c_re;
    double q_im = -c_im;
    double qn   = q_re * q_re + q_im * q_im;

    // w = num / den
    double w_re = (n_re * q_re + n_im * q_im) / qn;
    double w_im = (n_im * q_re - n_re * q_im) / qn;

    // U[t] = d * w
    double u_re = d_re * w_re - d_im * w_im;
    double u_im = d_re * w_im + d_im * w_re;

    out[t]      = (float)u_re;   // real part block
    out[nt + t] = (float)u_im;   // imag part block
}

extern "C" void kernel_launch(void* const* d_in, const int* in_sizes, int n_in,
                              void* d_out, int out_size, void* d_ws, size_t ws_size,
                              hipStream_t stream) {
    (void)in_sizes; (void)n_in; (void)d_ws; (void)ws_size;

    const float* pk  = (const float*)d_in[0];
    const float* TAx = (const float*)d_in[1];
    const float* TAy = (const float*)d_in[2];
    const float* fc  = (const float*)d_in[3];
    // d_in[4] = nt (device int) — host-side value derived from out_size instead.
    const int*   dtp = (const int*)d_in[5];

    float* out = (float*)d_out;
    int nt = out_size / 2;  // output = concat(real[nt], imag[nt])

    const int block = 256;
    const int grid  = (nt + block - 1) / block;
    slab1d_closed_form_kernel<<<grid, block, 0, stream>>>(pk, TAx, TAy, fc, dtp, out, nt);
}